// Round 8
// baseline (91.851 us; speedup 1.0000x reference)
//
#include <hip/hip_runtime.h>
#include <hip/hip_bf16.h>

#define B_DIM 16384
#define P_DIM 4096
#define D_DIM 256
#define BM 256
#define BN 256
#define BK 32
#define NT (D_DIM / BK)   // 8 K-steps

typedef float f32x4 __attribute__((ext_vector_type(4)));
typedef __bf16 bf16x8 __attribute__((ext_vector_type(8)));

__device__ __forceinline__ unsigned short f2bf_rne(float f) {
  unsigned int u = __builtin_bit_cast(unsigned int, f);
  u += 0x7fffu + ((u >> 16) & 1u);
  return (unsigned short)(u >> 16);
}

// One wave per row: fp32 -> bf16 conversion + fp32 row sum-of-squares.
__global__ __launch_bounds__(256) void prep_kernel(
    const float* __restrict__ x, const float* __restrict__ p,
    unsigned short* __restrict__ xb, unsigned short* __restrict__ pb,
    float* __restrict__ xsq, float* __restrict__ psq) {
  int row  = blockIdx.x * 4 + (threadIdx.x >> 6);
  int lane = threadIdx.x & 63;
  const float4* src;
  unsigned short* dst;
  float* sq;
  if (row < B_DIM) {
    src = (const float4*)(x + (size_t)row * D_DIM);
    dst = xb + (size_t)row * D_DIM;
    sq  = xsq + row;
  } else {
    int r = row - B_DIM;
    src = (const float4*)(p + (size_t)r * D_DIM);
    dst = pb + (size_t)r * D_DIM;
    sq  = psq + r;
  }
  float4 v = src[lane];
  ushort4 o;
  o.x = f2bf_rne(v.x); o.y = f2bf_rne(v.y);
  o.z = f2bf_rne(v.z); o.w = f2bf_rne(v.w);
  ((ushort4*)dst)[lane] = o;
  float s = v.x * v.x + v.y * v.y + v.z * v.z + v.w * v.w;
  #pragma unroll
  for (int off = 32; off > 0; off >>= 1) s += __shfl_down(s, off);
  if (lane == 0) *sq = s;
}

__device__ __forceinline__ void async16(const unsigned short* g, const void* l) {
  __builtin_amdgcn_global_load_lds(
      (const __attribute__((address_space(1))) void*)g,
      (__attribute__((address_space(3))) void*)l,
      16, 0, 0);
}

// 256x256 tile, 8 waves (2x4), BK=32, dbuf 64KB LDS, counted-vmcnt pipeline.
// R8 change vs R7: epilogue transposes each 16x64 sub-tile through dead
// staging LDS so every store instruction writes 256B-contiguous row
// segments (full 128B L2 lines) -> no L2 write-allocate HBM reads.
__global__ __launch_bounds__(512, 2) void dist_gemm(
    const unsigned short* __restrict__ A,   // [B_DIM][D_DIM] bf16 bits
    const unsigned short* __restrict__ Bm,  // [P_DIM][D_DIM] bf16 bits
    const float* __restrict__ xsq, const float* __restrict__ psq,
    float* __restrict__ out) {
  __shared__ __align__(16) char lds[2][2][16384];  // [buf][A|B][256r x 64B]

  const int tid  = threadIdx.x;
  const int w    = tid >> 6;        // 0..7
  const int lane = tid & 63;
  const int bid  = blockIdx.x;

  // XCD-chunked bijective swizzle: 1024 blocks, 8 XCDs, 128 blocks each.
  const int swz = (bid & 7) * 128 + (bid >> 3);
  const int bm  = swz >> 4;   // 0..63
  const int bn  = swz & 15;   // 0..15

  const int wr = w >> 2;      // 0..1  (row half: 128 rows)
  const int wc = w & 3;       // 0..3  (col quarter: 64 cols)

  // ---- staging geometry (linear LDS dest, pre-swizzled global source) ----
  const int rstg = w * 16 + (lane >> 2);               // + l*128
  const int cstg = (((lane & 3) << 4) ^ ((rstg & 3) << 4)) >> 1;  // elem col
  const unsigned short* aP[2];
  const unsigned short* bP[2];
  #pragma unroll
  for (int l = 0; l < 2; ++l) {
    aP[l] = A  + (size_t)(bm * BM + l * 128 + rstg) * D_DIM + cstg;
    bP[l] = Bm + (size_t)(bn * BN + l * 128 + rstg) * D_DIM + cstg;
  }

#define STAGE(bufi, ktE) do { _Pragma("unroll")                                \
    for (int l = 0; l < 2; ++l) {                                              \
      async16(aP[l] + (ktE), (const void*)(&lds[bufi][0][0] + l * 8192 + w * 1024)); \
      async16(bP[l] + (ktE), (const void*)(&lds[bufi][1][0] + l * 8192 + w * 1024)); \
    } } while (0)

  // ---- fragment read geometry ----
  const int arow = wr * 128 + (lane & 15);
  const int brow = wc * 64 + (lane & 15);
  const int koff = ((lane >> 4) << 4) ^ ((lane & 3) << 4);

  f32x4 acc[8][4];
  #pragma unroll
  for (int m = 0; m < 8; ++m)
    #pragma unroll
    for (int n = 0; n < 4; ++n) acc[m][n] = 0.0f;

  // Prologue: stage k-tile 0 into buf 0.
  STAGE(0, 0);
  asm volatile("s_waitcnt vmcnt(0)" ::: "memory");
  __builtin_amdgcn_s_barrier();
  __builtin_amdgcn_sched_barrier(0);

  #pragma unroll
  for (int t = 0; t < NT; ++t) {
    if (t < NT - 1) STAGE((t + 1) & 1, (t + 1) * BK);
    if (t > 0) {
      if (t < NT - 1) asm volatile("s_waitcnt vmcnt(4)" ::: "memory");
      else            asm volatile("s_waitcnt vmcnt(0)" ::: "memory");
      __builtin_amdgcn_s_barrier();
      __builtin_amdgcn_sched_barrier(0);
    }
    const char* La = &lds[t & 1][0][0];
    const char* Lb = &lds[t & 1][1][0];
    bf16x8 av[8], bv[4];
    #pragma unroll
    for (int m = 0; m < 8; ++m)
      av[m] = *(const bf16x8*)(La + (arow + m * 16) * 64 + koff);
    #pragma unroll
    for (int n = 0; n < 4; ++n)
      bv[n] = *(const bf16x8*)(Lb + (brow + n * 16) * 64 + koff);
    #pragma unroll
    for (int m = 0; m < 8; ++m)
      #pragma unroll
      for (int n = 0; n < 4; ++n)
        acc[m][n] = __builtin_amdgcn_mfma_f32_16x16x32_bf16(bv[n], av[m], acc[m][n], 0, 0, 0);
    if (t < NT - 1) {
      __builtin_amdgcn_sched_barrier(0);
      __builtin_amdgcn_s_barrier();   // all waves done reading buf t
      __builtin_amdgcn_sched_barrier(0);
    }
  }

  // ---- Epilogue with LDS transpose -> 256B contiguous store segments ----
  // Swapped-D layout: lane holds xrow = m*16 + (lane&15),
  // pcols = n*16 + (lane>>4)*4 + j. Per m, transpose 16x64 fp32 through
  // wave-private 4KB scratch in the DEAD buf-0 staging LDS (last K-step
  // reads buf 1 only; barrier at t=7 entry ordered all buf-0 reads before).
  const int xrowB = bm * BM + wr * 128;
  const int pcolB = bn * BN + wc * 64;
  const int rL = lane & 15;
  const int hL = lane >> 4;
  float* scr = (float*)(&lds[0][0][0] + w * 4096);   // 8 waves x 4KB = buf 0

  f32x4 ps[4];
  #pragma unroll
  for (int n = 0; n < 4; ++n)
    ps[n] = *(const f32x4*)(psq + pcolB + n * 16 + hL * 4);

  #pragma unroll
  for (int m = 0; m < 8; ++m) {
    const float xs = xsq[xrowB + m * 16 + rL];
    // WAR: previous m's scratch reads must retire before overwrite.
    asm volatile("s_waitcnt lgkmcnt(0)" ::: "memory");
    __builtin_amdgcn_sched_barrier(0);
    #pragma unroll
    for (int n = 0; n < 4; ++n) {
      f32x4 v;
      #pragma unroll
      for (int j = 0; j < 4; ++j) {
        float d = fmaf(-2.0f, acc[m][n][j], xs + ps[n][j]);
        v[j] = __builtin_sqrtf(fmaxf(d, 0.0f));
      }
      const int c4 = n * 4 + hL;                      // f32x4-unit col 0..15
      *(f32x4*)(scr + ((size_t)rL * 16 + (c4 ^ rL)) * 4) = v;
    }
    asm volatile("s_waitcnt lgkmcnt(0)" ::: "memory");
    __builtin_amdgcn_sched_barrier(0);
    #pragma unroll
    for (int q = 0; q < 4; ++q) {
      const int rq = q * 4 + hL;                      // row 0..15
      f32x4 vv = *(const f32x4*)(scr + ((size_t)rq * 16 + (rL ^ rq)) * 4);
      // 16 lanes (rL) x 16B = 256B contiguous per row; 4 rows per instr.
      *(f32x4*)(out + (size_t)(xrowB + m * 16 + rq) * P_DIM + pcolB + rL * 4) = vv;
    }
  }
#undef STAGE
}

extern "C" void kernel_launch(void* const* d_in, const int* in_sizes, int n_in,
                              void* d_out, int out_size, void* d_ws, size_t ws_size,
                              hipStream_t stream) {
  const float* x = (const float*)d_in[0];
  const float* p = (const float*)d_in[1];
  float* out = (float*)d_out;

  char* ws = (char*)d_ws;
  unsigned short* xb = (unsigned short*)ws;                                // 8 MB
  unsigned short* pb = (unsigned short*)(ws + (size_t)B_DIM * D_DIM * 2);  // 2 MB
  float* xsq = (float*)(ws + (size_t)(B_DIM + P_DIM) * D_DIM * 2);
  float* psq = xsq + B_DIM;

  prep_kernel<<<(B_DIM + P_DIM) / 4, 256, 0, stream>>>(x, p, xb, pb, xsq, psq);

  dist_gemm<<<(B_DIM / BM) * (P_DIM / BN), 512, 0, stream>>>(xb, pb, xsq, psq, out);
}